// Round 1
// 127.570 us; speedup vs baseline: 1.0008x; 1.0008x over previous
//
#include <hip/hip_runtime.h>
#include <stdint.h>

#define NCLS   80
#define HWTOT  21824
#define MBOX   100

// flat f32 output layout (return-order concat)
#define REG_OFF 28633088ull   // 16*21824*82
#define IND_OFF 30728192ull   // + 16*21824*6
#define NB_OFF  31077376ull   // + 16*21824

__global__ __launch_bounds__(256)
void sapd_targets(const float* __restrict__ gt, float* __restrict__ out)
{
    const int tid = threadIdx.x;
    const int c   = blockIdx.x;   // chunk id within batch, 0..85
    const int b   = blockIdx.y;   // batch 0..15

    // chunk -> (level, pixel0, level base). Chunks never cross level bounds.
    int lvl, pix0, base;
    if      (c < 64) { lvl = 0; pix0 = c << 8;        base = 0;     }
    else if (c < 80) { lvl = 1; pix0 = (c - 64) << 8; base = 16384; }
    else if (c < 84) { lvl = 2; pix0 = (c - 80) << 8; base = 20480; }
    else if (c < 85) { lvl = 3; pix0 = 0;             base = 21504; }
    else             { lvl = 4; pix0 = 0;             base = 21760; }

    const int   l2fw   = 7 - lvl;        // fw: 128,64,32,16,8
    const int   fw     = 1 << l2fw;
    const float fs     = (float)(8 << lvl);
    const int   chunkN = (lvl == 4) ? 64 : 256;

    const size_t rowbase = (size_t)b * HWTOT + base + pix0;  // always even

    __shared__ uint32_t sBB[MBOX];     // packed shrunk bounds (u8 x4)
    __shared__ float    sArea[MBOX];
    __shared__ int      sValid[MBOX];
    __shared__ float4   sBox[MBOX];    // original image-space coords
    __shared__ int      sLab[MBOX];
    __shared__ float2   sCull[MBOX];   // {bounds as float bits, area}
    __shared__ int      sOrig[MBOX];
    __shared__ int      sN;
    __shared__ float2   sSP[256];      // {soft, posf} per row (for reg loop)
    __shared__ float    rReg[256 * 4];

    // ---- phase 1: per-box precompute. gt load is the FIRST memory op ----
    if (tid < MBOX) {
        const float* g = gt + ((size_t)b * MBOX + tid) * 5;
        float x1 = g[0], y1 = g[1], x2 = g[2], y2 = g[3], lab = g[4];
        int valid = (fabsf(x1) + fabsf(y1) + fabsf(x2) + fabsf(y2)) > 0.0f;
        float area = (x2 - x1) * (y2 - y1);
        float bx1 = x1 / fs, by1 = y1 / fs, bx2 = x2 / fs, by2 = y2 / fs;
        float cx = (bx1 + bx2) * 0.5f, cy = (by1 + by2) * 0.5f;
        float hw = (bx2 - bx1) * 0.5f * 0.2f, hh = (by2 - by1) * 0.5f * 0.2f;
        float px1 = fmaxf(floorf(cx - hw), 0.0f);
        float py1 = fmaxf(floorf(cy - hh), 0.0f);
        float px2 = fminf(ceilf(cx + hw), (float)fw);
        float py2 = fminf(ceilf(cy + hh), (float)fw);
        uint32_t bb = (uint32_t)px1 | ((uint32_t)py1 << 8) |
                      ((uint32_t)px2 << 16) | ((uint32_t)py2 << 24);
        sBB[tid]    = bb;
        sArea[tid]  = area;
        sValid[tid] = valid;
        sBox[tid]   = make_float4(x1, y1, x2, y2);
        sLab[tid]   = (int)lab;
    }
    __syncthreads();

    // num_boxes: lvl-4 blocks (one per batch), thread 64 idle in phase 3
    if (lvl == 4 && tid == 64) {
        int cnt = 0;
        for (int m = 0; m < MBOX; ++m) cnt += sValid[m];
        out[NB_OFF + b] = (float)cnt;
    }

    // ---- phase 2: wave-0 order-preserving row-band cull ----
    if (tid < 64) {
        const int lane = tid;
        const int ry0 = pix0 >> l2fw;
        const int ry1 = ry0 + (chunkN >> l2fw);
        int n0;
        {
            int m = lane;   // m < 64 < MBOX always
            uint32_t bb = sBB[m];
            int ix1 = bb & 255, iy1 = (bb >> 8) & 255, ix2 = (bb >> 16) & 255, iy2 = bb >> 24;
            bool pred = sValid[m] && (ix2 > ix1) && (iy2 > ry0) && (iy1 < ry1);
            unsigned long long mk = __ballot(pred);
            n0 = __popcll(mk);
            if (pred) {
                int p = __popcll(mk & ((1ull << lane) - 1ull));
                sCull[p] = make_float2(__uint_as_float(bb), sArea[m]);
                sOrig[p] = m;
            }
        }
        {
            int m = 64 + lane;
            bool pred = false;
            uint32_t bb = 0;
            float ar = 0.0f;
            if (m < MBOX) {
                bb = sBB[m]; ar = sArea[m];
                int ix1 = bb & 255, iy1 = (bb >> 8) & 255, ix2 = (bb >> 16) & 255, iy2 = bb >> 24;
                pred = sValid[m] && (ix2 > ix1) && (iy2 > ry0) && (iy1 < ry1);
            }
            unsigned long long mk = __ballot(pred);
            if (pred) {
                int p = n0 + __popcll(mk & ((1ull << lane) - 1ull));
                sCull[p] = make_float2(__uint_as_float(bb), ar);
                sOrig[p] = m;
            }
            if (lane == 0) sN = n0 + __popcll(mk);
        }
    }
    __syncthreads();

    // ---- phase 3: per-pixel argmin + target math. Results kept in REGISTERS
    //      for the post-zero fixup; soft/posf also go to LDS for the reg loop.
    float soft = 1.0f, posf = 0.0f;
    int   tgtcol = 0, posflag = 0;
    if (tid < chunkN) {
        const int p  = pix0 + tid;
        const int px = p & (fw - 1);
        const int py = p >> l2fw;
        float bestA = 1e30f; int bestI = -1;
        const int n = sN;
        for (int i = 0; i < n; ++i) {
            float2 e = sCull[i];
            uint32_t bb = __float_as_uint(e.x);
            int x1 = bb & 255, y1 = (bb >> 8) & 255, x2 = (bb >> 16) & 255, y2 = bb >> 24;
            bool hit = (px >= x1) & (px < x2) & (py >= y1) & (py < y2);
            bool upd = hit & (e.y < bestA);   // strict < keeps first (orig-order) on ties
            bestA = upd ? e.y : bestA;
            bestI = upd ? i : bestI;
        }
        bool pos = bestI >= 0;
        int orig = pos ? sOrig[bestI] : 0;
        float4 bx = sBox[orig];
        float sx = ((float)px + 0.5f) * fs;
        float sy = ((float)py + 0.5f) * fs;
        float l  = sx - bx.x, t = sy - bx.y, r = bx.z - sx, bt = bx.w - sy;
        float inv4s = 1.0f / (4.0f * fs);   // power of two: exact vs reference divide
        posf = pos ? 1.0f : 0.0f;
        const float eps = 1e-6f;
        float a1 = fminf(l, r) / fmaxf(fmaxf(l, r), eps);
        a1 = fminf(fmaxf(a1, 0.0f), 1.0f);
        float a2 = fminf(t, bt) / fmaxf(fmaxf(t, bt), eps);
        a2 = fminf(fmaxf(a2, 0.0f), 1.0f);
        float cent = sqrtf(a1 * a2);
        soft = pos ? cent : 1.0f;
        tgtcol  = pos ? sLab[orig] : 0;     // only used when posflag
        posflag = pos ? 1 : 0;
        sSP[tid] = make_float2(soft, posf);
        rReg[tid * 4 + 0] = l  * inv4s * posf;
        rReg[tid * 4 + 1] = t  * inv4s * posf;
        rReg[tid * 4 + 2] = r  * inv4s * posf;
        rReg[tid * 4 + 3] = bt * inv4s * posf;
        out[IND_OFF + rowbase + tid] = pos ? (float)((bestI >= 0) ? sOrig[bestI] : 0) : -1.0f;
    }

    // ---- phase 4a: pure streaming zero pass over the block's cls region ----
    // chunkN rows x 82 cols, flat float4 loop: no LDS reads, no divides, no
    // per-element one-hot logic. rowbase even -> 16B aligned; (82*chunkN)%4==0.
    {
        float4* o4 = (float4*)(out + rowbase * 82);
        const int n4 = (chunkN * 82) >> 2;            // 5248 or 1312
        const float4 z = make_float4(0.0f, 0.0f, 0.0f, 0.0f);
        for (int i = tid; i < n4; i += 256) o4[i] = z;
    }

    // barrier drains vmcnt(0): all zero stores are at the L2 coherence point
    // (same CU -> same XCD L2), so the sparse fixups below are safely ordered.
    __syncthreads();

    // ---- phase 4b: sparse per-row fixup (registers survive the barrier) ----
    // cls row = 80 one-hot + soft + posf. Zeros already written; patch:
    //   cols 80..81 <- {soft, posf}   (float2: index (rowbase+tid)*82+80 is even)
    //   col  tgtcol <- 1.0f when pos
    if (tid < chunkN) {
        const size_t row0 = (rowbase + (size_t)tid) * 82ull;
        *(float2*)(out + row0 + 80) = make_float2(soft, posf);
        if (posflag) out[row0 + tgtcol] = 1.0f;
    }

    // ---- phase 4c: reg region — contiguous float4 fill from LDS (unchanged) ----
    {
        float4* o4 = (float4*)(out + REG_OFF + rowbase * 6);   // 16B-aligned
        const int n4 = (chunkN * 6) >> 2;   // 384 or 96
        for (int i = tid; i < n4; i += 256) {
            int idx = i << 2;
            float v[4];
            #pragma unroll
            for (int k = 0; k < 4; ++k) {
                int id  = idx + k;
                int row = (int)((unsigned)id / 6u);
                int col = id - row * 6;
                float2 m = sSP[row];
                v[k] = (col < 4) ? rReg[row * 4 + col] : ((col == 4) ? m.x : m.y);
            }
            o4[i] = make_float4(v[0], v[1], v[2], v[3]);
        }
    }
}

extern "C" void kernel_launch(void* const* d_in, const int* in_sizes, int n_in,
                              void* d_out, int out_size, void* d_ws, size_t ws_size,
                              hipStream_t stream)
{
    const float* gt = (const float*)d_in[0];
    float* out = (float*)d_out;
    sapd_targets<<<dim3(86, 16), 256, 0, stream>>>(gt, out);
}